// Round 15
// baseline (660.112 us; speedup 1.0000x reference)
//
#include <hip/hip_runtime.h>

// ---------------- problem constants ----------------
#define NTOK 2048
#define TT   16
#define EE   512
#define HIDD 256
#define G4   1024
#define NLVL 16
#define KLVL 128
#define INV2048 (1.0f/2048.0f)

typedef _Float16 v8h __attribute__((ext_vector_type(8)));
typedef _Float16 v4h __attribute__((ext_vector_type(4)));
typedef float    v4f __attribute__((ext_vector_type(4)));

__device__ __forceinline__ v4f mfma16(v8h a, v8h b, v4f c) {
  return __builtin_amdgcn_mfma_f32_16x16x32_f16(a, b, c, 0, 0, 0);
}

__device__ __forceinline__ float fsig(float x) {
  return 1.0f / (1.0f + __expf(-x));
}
__device__ __forceinline__ float ftanh(float x) {
  float ax = fabsf(x);
  float e  = __expf(-2.0f * ax);
  float t  = (1.0f - e) / (1.0f + e);
  return copysignf(t, x);
}

__device__ __forceinline__ void split8(const v4f& w0, const v4f& w1, v8h& hi, v8h& lo) {
#pragma unroll
  for (int u = 0; u < 4; ++u) {
    float v = w0[u]; _Float16 h = (_Float16)v;
    hi[u] = h; lo[u] = (_Float16)((v - (float)h) * 2048.0f);
  }
#pragma unroll
  for (int u = 0; u < 4; ++u) {
    float v = w1[u]; _Float16 h = (_Float16)v;
    hi[4+u] = h; lo[4+u] = (_Float16)((v - (float)h) * 2048.0f);
  }
}

__device__ __forceinline__ v8h cvt8(const v4f& w0, const v4f& w1) {
  v8h r;
#pragma unroll
  for (int u = 0; u < 4; ++u) { r[u] = (_Float16)w0[u]; r[4+u] = (_Float16)w1[u]; }
  return r;
}

// ---------------- K-1: normalize parent_valid to uchar[16384] ---------------
__global__ __launch_bounds__(256) void knorm(const void* __restrict__ pv_raw,
                                             unsigned char* __restrict__ pv8) {
  __shared__ int mode;
  const int tid = threadIdx.x;
  if (tid == 0) mode = 0;
  __syncthreads();
  const unsigned* pu = (const unsigned*)pv_raw;
  int local = 0;
  for (int i = tid; i < 4096; i += 256) {
    unsigned v = pu[i];
    if (v == 0x3F800000u) { local = 2; break; }
    if (v > 1u) local = 1;
  }
  if (local) atomicMax(&mode, local);
  __syncthreads();
  const int m = mode;
  const unsigned char* pb = (const unsigned char*)pv_raw;
  const float* pf = (const float*)pv_raw;
  const int* pi = (const int*)pv_raw;
  for (int i = tid; i < NTOK * 8; i += 256) {
    unsigned char v;
    if (m == 1)      v = (pb[i] != 0);
    else if (m == 2) v = (pf[i] != 0.0f);
    else             v = (pi[i] != 0);
    pv8[i] = v;
  }
}

// ---------------- K0: weight packing (vectorized) ---------------------------
__global__ __launch_bounds__(256) void kw_cvt(
    const float* __restrict__ a0, _Float16* __restrict__ f0,
    const float* __restrict__ a1, _Float16* __restrict__ f1,
    const float* __restrict__ a2, _Float16* __restrict__ f2,
    const float* __restrict__ a3, _Float16* __restrict__ f3) {
  const int t = blockIdx.x * 256 + threadIdx.x;
  if (t < 32768) {
    const int row = t >> 5, col8 = (t & 31) * 8;
    const int fc = row >> 4, l15 = row & 15;
    const int kk = col8 >> 5, lq = (col8 >> 3) & 3;
    const int lane8 = (lq * 16 + l15) * 8;
    const size_t srow = (size_t)row * 256 + col8;
    {
      v4f x0 = *(const v4f*)(a0 + srow), x1 = *(const v4f*)(a0 + srow + 4);
      *(v8h*)(f0 + (size_t)(fc * 8 + kk) * 512 + lane8) = cvt8(x0, x1);
    }
    {
      v4f x0 = *(const v4f*)(a1 + srow), x1 = *(const v4f*)(a1 + srow + 4);
      v8h hi, lo; split8(x0, x1, hi, lo);
      _Float16* d = f1 + (size_t)(fc * 8 + kk) * 1024 + lane8;
      *(v8h*)d = hi; *(v8h*)(d + 512) = lo;
    }
    {
      v4f x0 = *(const v4f*)(a2 + srow), x1 = *(const v4f*)(a2 + srow + 4);
      v8h hi, lo; split8(x0, x1, hi, lo);
      _Float16* d = f2 + (size_t)(fc * 8 + kk) * 1024 + lane8;
      *(v8h*)d = hi; *(v8h*)(d + 512) = lo;
    }
  } else {
    const int k = t - 32768;
    const int row = k >> 6, col8 = (k & 63) * 8;
    const int fc = row >> 4, l15 = row & 15;
    const int kk = col8 >> 5, lq = (col8 >> 3) & 3;
    const size_t srow = (size_t)row * 512 + col8;
    v4f x0 = *(const v4f*)(a3 + srow), x1 = *(const v4f*)(a3 + srow + 4);
    *(v8h*)(f3 + (size_t)(fc * 16 + kk) * 512 + (lq * 16 + l15) * 8) = cvt8(x0, x1);
  }
}

// ---------------- K1: Xg(fp16) = tokens_half @ Wih_tok^T (+biases) ----------
__global__ __launch_bounds__(512, 1) void kg2(const float* __restrict__ A,
                                              const _Float16* __restrict__ WtH,
                                              const float* __restrict__ b1,
                                              const float* __restrict__ b2,
                                              _Float16* __restrict__ Xg, int h) {
  __shared__ _Float16 As[64 * 520];
  const int tid  = threadIdx.x;
  const int lane = tid & 63;
  const int nq   = tid >> 6;
  const int l15  = lane & 15;
  const int lq   = lane >> 4;
  const int m0   = blockIdx.x * 64;

#pragma unroll
  for (int p = 0; p < 4; ++p) {
    const int row  = p * 16 + (tid >> 5);
    const int col0 = (tid & 31) * 16;
    const int ar   = m0 + row;
    const int tokrow = (ar & 2047) * 16 + h * 8 + (ar >> 11);
    const float* s = A + (size_t)tokrow * EE + col0;
    v4f x0 = *(const v4f*)s, x1 = *(const v4f*)(s + 4);
    v4f x2 = *(const v4f*)(s + 8), x3 = *(const v4f*)(s + 12);
    _Float16* d = As + row * 520 + col0;
    *(v8h*)d       = cvt8(x0, x1);
    *(v8h*)(d + 8) = cvt8(x2, x3);
  }
  __syncthreads();

  v4f acc[4][8];
#pragma unroll
  for (int n = 0; n < 8; ++n) {
    const int col = (nq * 8 + n) * 16 + l15;
    const float bb = b1[col] + b2[col];
#pragma unroll
    for (int m = 0; m < 4; ++m) acc[m][n] = (v4f){bb, bb, bb, bb};
  }

#pragma unroll 4
  for (int kk = 0; kk < 16; ++kk) {
    v8h af[4];
#pragma unroll
    for (int m = 0; m < 4; ++m)
      af[m] = *(const v8h*)(As + (m * 16 + l15) * 520 + kk * 32 + lq * 8);
#pragma unroll
    for (int n = 0; n < 8; ++n) {
      const int fc = nq * 8 + n;
      v8h bh = *(const v8h*)(WtH + (size_t)(fc * 16 + kk) * 512 + lane * 8);
#pragma unroll
      for (int m = 0; m < 4; ++m) acc[m][n] = mfma16(af[m], bh, acc[m][n]);
    }
  }

#pragma unroll
  for (int m = 0; m < 4; ++m)
#pragma unroll
    for (int n = 0; n < 8; ++n) {
      const int row = m0 + m * 16 + lq * 4;
      const int col = (nq * 8 + n) * 16 + l15;
      v4h o;
#pragma unroll
      for (int r = 0; r < 4; ++r) o[r] = (_Float16)acc[m][n][r];
      *(v4h*)(Xg + ((size_t)(row >> 2) * G4 + col) * 4) = o;
    }
}

// ---------------- K2: token LSTM recurrence (LDS-staged weights) ------------
// 128 blocks x 16 rows x 8 waves. Per kk-slice (64KB) the whole block stages
// weights cooperatively (coalesced 1KB-per-wave-instruction loads + conflict-
// free ds_write_b128), double-buffered in LDS; MFMAs read frags from LDS.
// 1 barrier/slice + 1 pre-cell-update barrier. Math identical to kr3.
__global__ __launch_bounds__(512, 1) void kr4(const _Float16* __restrict__ Xg,
                                              const _Float16* __restrict__ WhhT,
                                              float* __restrict__ Hst,
                                              float* __restrict__ Cst,
                                              _Float16* __restrict__ emb, int q) {
  __shared__ _Float16 wbuf[2][32768];   // 2 x 64 KB weight slices
  __shared__ float hbuf[16 * 260];      // 16.6 KB
  const int tid  = threadIdx.x;
  const int lane = tid & 63;
  const int w    = tid >> 6;       // 0..7
  const int wv   = w & 3;
  const int jh   = w >> 2;
  const int l15  = lane & 15;
  const int lq   = lane >> 4;
  const int r0   = blockIdx.x * 16;

  v4f c[2];
  if (q) {
#pragma unroll
    for (int j2 = 0; j2 < 2; ++j2) {
      const int feat = 16 * (wv + 4 * (2 * jh + j2)) + l15;
#pragma unroll
      for (int r = 0; r < 4; ++r)
        c[j2][r] = Cst[(size_t)(r0 + lq * 4 + r) * HIDD + feat];
    }
    for (int idx = tid; idx < 4096; idx += 512)
      hbuf[(idx >> 8) * 260 + (idx & 255)] = Hst[(size_t)(r0 + (idx >> 8)) * HIDD + (idx & 255)];
  } else {
    c[0] = (v4f){0.f, 0.f, 0.f, 0.f};
    c[1] = (v4f){0.f, 0.f, 0.f, 0.f};
  }

  // Xg prefetch for tl = 0
  v4h xp[4][2];
  {
    const size_t xrow = (size_t)((r0 >> 2) + lq) * G4;
#pragma unroll
    for (int g = 0; g < 4; ++g)
#pragma unroll
      for (int j2 = 0; j2 < 2; ++j2) {
        const int col = 256 * g + 16 * (wv + 4 * (2 * jh + j2)) + l15;
        xp[g][j2] = *(const v4h*)(Xg + (xrow + col) * 4);
      }
  }

  // staging: thread handles chunks ch = tid + 512*i (16B each); for slice kk:
  //   src = WhhT + ((ch>>6)*8 + kk)*512 + (ch&63)*8   (contiguous 1KB per wave-instr)
  //   lds = wbuf[buf] + ch*8
  v8h rS[8];
#pragma unroll
  for (int i = 0; i < 8; ++i) {
    const int ch = tid + 512 * i;
    rS[i] = *(const v8h*)(WhhT + (size_t)((ch >> 6) * 8 + 0) * 512 + (ch & 63) * 8);
  }
  __syncthreads();   // hbuf init visible

#pragma unroll 1
  for (int tl = 0; tl < 8; ++tl) {
    const bool have_h = (q > 0) || (tl > 0);
    v4f acc[4][2];
#pragma unroll
    for (int g = 0; g < 4; ++g)
#pragma unroll
      for (int j2 = 0; j2 < 2; ++j2) {
        v4f a;
#pragma unroll
        for (int r = 0; r < 4; ++r) a[r] = (float)xp[g][j2][r];
        acc[g][j2] = a;
      }
    if (tl < 7) {
      const size_t xrow = (size_t)((tl + 1) * 512 + (r0 >> 2) + lq) * G4;
#pragma unroll
      for (int g = 0; g < 4; ++g)
#pragma unroll
        for (int j2 = 0; j2 < 2; ++j2) {
          const int col = 256 * g + 16 * (wv + 4 * (2 * jh + j2)) + l15;
          xp[g][j2] = *(const v4h*)(Xg + (xrow + col) * 4);
        }
    }

#pragma unroll
    for (int s = 0; s < 8; ++s) {
      _Float16* wb = wbuf[s & 1];
      // write current slice (kk = s) from regs to LDS
#pragma unroll
      for (int i = 0; i < 8; ++i)
        *(v8h*)(wb + (tid + 512 * i) * 8) = rS[i];
      // issue loads for next slice (kk = (s+1)&7) into rS
      {
        const int kkn = (s + 1) & 7;
#pragma unroll
        for (int i = 0; i < 8; ++i) {
          const int ch = tid + 512 * i;
          rS[i] = *(const v8h*)(WhhT + (size_t)((ch >> 6) * 8 + kkn) * 512 + (ch & 63) * 8);
        }
      }
      __syncthreads();   // slice s staged (and rS loads drained)
      if (have_h) {
        const int ko = s * 32 + lq * 8;
        v4f w0 = *(const v4f*)(hbuf + l15 * 260 + ko);
        v4f w1 = *(const v4f*)(hbuf + l15 * 260 + ko + 4);
        v8h ah = cvt8(w0, w1);
#pragma unroll
        for (int g = 0; g < 4; ++g)
#pragma unroll
          for (int j2 = 0; j2 < 2; ++j2) {
            const int fc = 16 * g + 8 * jh + 4 * j2 + wv;
            v8h b = *(const v8h*)(wb + fc * 512 + lane * 8);
            acc[g][j2] = mfma16(ah, b, acc[g][j2]);
          }
      }
    }
    __syncthreads();   // all hbuf reads (slice 7 computes) done before overwrite

#pragma unroll
    for (int j2 = 0; j2 < 2; ++j2) {
      const int feat = 16 * (wv + 4 * (2 * jh + j2)) + l15;
#pragma unroll
      for (int r = 0; r < 4; ++r) {
        const int rr = lq * 4 + r;
        float cn = fsig(acc[1][j2][r]) * c[j2][r] + fsig(acc[0][j2][r]) * ftanh(acc[2][j2][r]);
        float hn = fsig(acc[3][j2][r]) * ftanh(cn);
        c[j2][r] = cn;
        hbuf[rr * 260 + feat] = hn;
        if (tl == 7) {
          const size_t grow = r0 + rr;
          if (!q) { Hst[grow * HIDD + feat] = hn; Cst[grow * HIDD + feat] = cn; }
          else    { emb[grow * HIDD + feat] = (_Float16)hn; }
        }
      }
    }
    // next step's first slice barrier makes these writes visible before reads
  }
}

// ---------------- K2b: P = emb @ Wih_ins^T + (bi+bh), fp32 tiled ------------
__global__ __launch_bounds__(512, 1) void kxi(const _Float16* __restrict__ emb,
                                              const _Float16* __restrict__ WihF,
                                              const float* __restrict__ bi,
                                              const float* __restrict__ bh,
                                              float* __restrict__ P) {
  __shared__ _Float16 As[64 * 264];
  const int tid  = threadIdx.x;
  const int lane = tid & 63;
  const int nq   = tid >> 6;
  const int l15  = lane & 15;
  const int lq   = lane >> 4;
  const int m0   = blockIdx.x * 64;

#pragma unroll
  for (int p = 0; p < 4; ++p) {
    const int idx = tid + 512 * p;
    const int row = idx >> 5;
    const int c8  = (idx & 31) * 8;
    *(v8h*)(As + row * 264 + c8) = *(const v8h*)(emb + (size_t)(m0 + row) * HIDD + c8);
  }
  __syncthreads();

  v4f acc[4][8];
#pragma unroll
  for (int n = 0; n < 8; ++n) {
    const int col = (nq * 8 + n) * 16 + l15;
    const float bb = bi[col] + bh[col];
#pragma unroll
    for (int m = 0; m < 4; ++m) acc[m][n] = (v4f){bb, bb, bb, bb};
  }

#pragma unroll 2
  for (int kk = 0; kk < 8; ++kk) {
    v8h af[4];
#pragma unroll
    for (int m = 0; m < 4; ++m)
      af[m] = *(const v8h*)(As + (m * 16 + l15) * 264 + kk * 32 + lq * 8);
#pragma unroll
    for (int n = 0; n < 8; ++n) {
      const int fc = nq * 8 + n;
      v8h bhf = *(const v8h*)(WihF + (size_t)(fc * 8 + kk) * 1024 + lane * 8);
#pragma unroll
      for (int m = 0; m < 4; ++m) acc[m][n] = mfma16(af[m], bhf, acc[m][n]);
    }
  }

#pragma unroll
  for (int m = 0; m < 4; ++m)
#pragma unroll
    for (int n = 0; n < 8; ++n) {
      const int row = m0 + m * 16 + lq * 4;
      const int col = (nq * 8 + n) * 16 + l15;
      *(v4f*)(P + ((size_t)(row >> 2) * G4 + col) * 4) = acc[m][n];
    }
}

// ---------------- K3a: appears scatter (32 blocks) --------------------------
__global__ __launch_bounds__(256) void kapp(const int* __restrict__ pidx,
                                            const unsigned char* __restrict__ pval,
                                            int* __restrict__ appears) {
  int e = blockIdx.x * 512 + threadIdx.x * 2;
#pragma unroll
  for (int u = 0; u < 2; ++u, ++e) {
    if (pval[e]) atomicAdd(appears + pidx[e], 1);
  }
}

// ---------------- K3b: one DAG level (32 blocks) ----------------------------
__global__ __launch_bounds__(256) void klevel(
    const float* __restrict__ P,
    const _Float16* __restrict__ WhhF,
    const int* __restrict__ pidx, const unsigned char* __restrict__ pval,
    float* __restrict__ H, float* __restrict__ C, int l) {
  __shared__ _Float16 h0s[16 * 264];
  __shared__ float    c0s[16 * 68];
  __shared__ int      pis[128];
  __shared__ unsigned char pvs[128];
  const int tid  = threadIdx.x;
  const int lane = tid & 63;
  const int wv   = tid >> 6;
  const int l15  = lane & 15;
  const int lq   = lane >> 4;
  const int b    = blockIdx.x;
  const int mf   = b >> 2;
  const int q    = b & 3;
  const int fi   = q * 4 + wv;

  if (tid < 128) {
    int rr = tid >> 3, p = tid & 7;
    int row = l * KLVL + mf * 16 + rr;
    pis[tid] = pidx[row * 8 + p];
    pvs[tid] = pval[row * 8 + p];
  }
  __syncthreads();
#pragma unroll 1
  for (int it = 0; it < 4; ++it) {
    int task = tid + 256 * it;
    int rr = task >> 6;
    int f4 = (task & 63) * 4;
    v4f hm = (v4f){-1e30f, -1e30f, -1e30f, -1e30f};
    bool any = false;
#pragma unroll
    for (int p = 0; p < 8; ++p) {
      if (pvs[rr * 8 + p]) {
        any = true;
        v4f hv = *(const v4f*)(H + (size_t)pis[rr * 8 + p] * HIDD + f4);
#pragma unroll
        for (int u = 0; u < 4; ++u) hm[u] = fmaxf(hm[u], hv[u]);
      }
    }
    if (!any) hm = (v4f){0.f, 0.f, 0.f, 0.f};
    v4h h4;
#pragma unroll
    for (int u = 0; u < 4; ++u) h4[u] = (_Float16)hm[u];
    *(v4h*)(h0s + rr * 264 + f4) = h4;
  }
  {
    int rr = tid >> 4;
    int cc = (tid & 15) * 4;
    int f4 = q * 64 + cc;
    v4f cm = (v4f){-1e30f, -1e30f, -1e30f, -1e30f};
    bool any = false;
#pragma unroll
    for (int p = 0; p < 8; ++p) {
      if (pvs[rr * 8 + p]) {
        any = true;
        v4f cv = *(const v4f*)(C + (size_t)pis[rr * 8 + p] * HIDD + f4);
#pragma unroll
        for (int u = 0; u < 4; ++u) cm[u] = fmaxf(cm[u], cv[u]);
      }
    }
    if (!any) cm = (v4f){0.f, 0.f, 0.f, 0.f};
    *(v4f*)(c0s + rr * 68 + cc) = cm;
  }
  __syncthreads();

  v4f acc[4];
  const int lrow4 = l * 32 + mf * 4 + lq;
#pragma unroll
  for (int g = 0; g < 4; ++g)
    acc[g] = *(const v4f*)(P + ((size_t)lrow4 * G4 + 256 * g + 16 * fi + l15) * 4);

#pragma unroll 1
  for (int kk = 0; kk < 8; ++kk) {
    const int ko = kk * 32 + lq * 8;
    v8h ah = *(const v8h*)(h0s + l15 * 264 + ko);
#pragma unroll
    for (int g = 0; g < 4; ++g) {
      const int fc = 16 * g + fi;
      acc[g] = mfma16(ah, *(const v8h*)(WhhF + (size_t)(fc * 8 + kk) * 1024 + lane * 8), acc[g]);
    }
  }
#pragma unroll
  for (int r = 0; r < 4; ++r) {
    int rr = lq * 4 + r;
    int n  = 16 * fi + l15;
    float c0 = c0s[rr * 68 + 16 * wv + l15];
    float cn = fsig(acc[1][r]) * c0 + fsig(acc[0][r]) * ftanh(acc[2][r]);
    float hn = fsig(acc[3][r]) * ftanh(cn);
    int grow = l * KLVL + mf * 16 + rr;
    H[(size_t)grow * HIDD + n] = hn;
    C[(size_t)grow * HIDD + n] = cn;
  }
}

// ---------------- K4a: partial root max (32 blocks x 64 rows) ---------------
__global__ __launch_bounds__(256) void kroot1(const float* __restrict__ H,
                                              const int* __restrict__ appears,
                                              float* __restrict__ pmax) {
  __shared__ int app[64];
  const int tid = threadIdx.x;
  const int rb  = blockIdx.x * 64;
  if (tid < 64) app[tid] = appears[rb + tid];
  __syncthreads();
  float m = -1e30f;
#pragma unroll 1
  for (int r = 0; r < 64; ++r) {
    if (app[r] == 0) m = fmaxf(m, H[(size_t)(rb + r) * HIDD + tid]);
  }
  pmax[blockIdx.x * 256 + tid] = m;
}

// ---------------- K4b: final combine + linear -------------------------------
__global__ __launch_bounds__(256) void kroot2(const float* __restrict__ pmax,
                                              const float* __restrict__ Wlin,
                                              const float* __restrict__ blin,
                                              float* __restrict__ out) {
  __shared__ float red[256];
  const int tid = threadIdx.x;
  float m = pmax[tid];
#pragma unroll 1
  for (int bb = 1; bb < 32; ++bb) m = fmaxf(m, pmax[bb * 256 + tid]);
  red[tid] = m * Wlin[tid];
  __syncthreads();
  if (tid == 0) {
    float s = 0.f;
    for (int i2 = 0; i2 < 256; ++i2) s += red[i2];
    out[0] = s + blin[0];
  }
}

// ---------------- launch ----------------------------------------------------
extern "C" void kernel_launch(void* const* d_in, const int* in_sizes, int n_in,
                              void* d_out, int out_size, void* d_ws, size_t ws_size,
                              hipStream_t stream) {
  const float* tokens  = (const float*)d_in[0];
  const int*   pidx    = (const int*)d_in[1];
  const void*  pvraw   = (const void*)d_in[2];
  const float* Wih_tok = (const float*)d_in[3];
  const float* Whh_tok = (const float*)d_in[4];
  const float* bih_tok = (const float*)d_in[5];
  const float* bhh_tok = (const float*)d_in[6];
  const float* Wih_ins = (const float*)d_in[7];
  const float* Whh_ins = (const float*)d_in[8];
  const float* bih_ins = (const float*)d_in[9];
  const float* bhh_ins = (const float*)d_in[10];
  const float* Wlin    = (const float*)d_in[11];
  const float* blin    = (const float*)d_in[12];

  char* ws = (char*)d_ws;
  const size_t OFF_XG    = 0;                       // fp16 half 33.5 MB (reused)
  const size_t OFF_H     = OFF_XG   + 33554432;
  const size_t OFF_C     = OFF_H    + 2097152;
  const size_t OFF_EMB   = OFF_C    + 2097152;      // fp16 1 MB
  const size_t OFF_P     = OFF_EMB  + 1048576;      // fp32 tiled 8 MB
  const size_t OFF_WHHT  = OFF_P    + 8388608;      // Whh_tok hi-dense 512 KB
  const size_t OFF_WIHIF = OFF_WHHT + 524288;       // ins split 1 MB each
  const size_t OFF_WHHIF = OFF_WIHIF + 1048576;
  const size_t OFF_WTH   = OFF_WHHIF + 1048576;     // Wih_tok hi-dense 1 MB
  const size_t OFF_APP   = OFF_WTH  + 1048576;
  const size_t OFF_PMX   = OFF_APP  + 8192;
  const size_t OFF_PV8   = OFF_PMX  + 32768;

  _Float16* Xg    = (_Float16*)(ws + OFF_XG);
  float*    Hbuf  = (float*)(ws + OFF_H);
  float*    Cbuf  = (float*)(ws + OFF_C);
  _Float16* emb   = (_Float16*)(ws + OFF_EMB);
  float*    Pbuf  = (float*)(ws + OFF_P);
  _Float16* WhhT  = (_Float16*)(ws + OFF_WHHT);
  _Float16* WihIF = (_Float16*)(ws + OFF_WIHIF);
  _Float16* WhhIF = (_Float16*)(ws + OFF_WHHIF);
  _Float16* WtH   = (_Float16*)(ws + OFF_WTH);
  int*      app   = (int*)(ws + OFF_APP);
  float*    pmx   = (float*)(ws + OFF_PMX);
  unsigned char* pv8 = (unsigned char*)(ws + OFF_PV8);

  hipMemsetAsync(ws + OFF_APP, 0, 8192, stream);

  knorm<<<dim3(1), dim3(256), 0, stream>>>(pvraw, pv8);
  kw_cvt<<<dim3(384), dim3(256), 0, stream>>>(Whh_tok, WhhT,
                                              Wih_ins, WihIF,
                                              Whh_ins, WhhIF,
                                              Wih_tok, WtH);
  kapp<<<dim3(32), dim3(256), 0, stream>>>(pidx, pv8, app);

  for (int h = 0; h < 2; ++h) {
    kg2<<<dim3(256), dim3(512), 0, stream>>>(tokens, WtH, bih_tok, bhh_tok, Xg, h);
    kr4<<<dim3(128), dim3(512), 0, stream>>>(Xg, WhhT, Hbuf, Cbuf, emb, h);
  }

  kxi<<<dim3(32), dim3(512), 0, stream>>>(emb, WihIF, bih_ins, bhh_ins, Pbuf);

  for (int l = 0; l < NLVL; ++l) {
    klevel<<<dim3(32), dim3(256), 0, stream>>>(Pbuf, WhhIF, pidx, pv8,
                                               Hbuf, Cbuf, l);
  }
  kroot1<<<dim3(32), dim3(256), 0, stream>>>(Hbuf, app, pmx);
  kroot2<<<dim3(1), dim3(256), 0, stream>>>(pmx, Wlin, blin, (float*)d_out);
}

// Round 16
// 494.173 us; speedup vs baseline: 1.3358x; 1.3358x over previous
//
#include <hip/hip_runtime.h>

// ---------------- problem constants ----------------
#define NTOK 2048
#define TT   16
#define EE   512
#define HIDD 256
#define G4   1024
#define NLVL 16
#define KLVL 128
#define INV2048 (1.0f/2048.0f)

typedef _Float16 v8h __attribute__((ext_vector_type(8)));
typedef _Float16 v4h __attribute__((ext_vector_type(4)));
typedef float    v4f __attribute__((ext_vector_type(4)));

__device__ __forceinline__ v4f mfma16(v8h a, v8h b, v4f c) {
  return __builtin_amdgcn_mfma_f32_16x16x32_f16(a, b, c, 0, 0, 0);
}

__device__ __forceinline__ float fsig(float x) {
  return 1.0f / (1.0f + __expf(-x));
}
__device__ __forceinline__ float ftanh(float x) {
  float ax = fabsf(x);
  float e  = __expf(-2.0f * ax);
  float t  = (1.0f - e) / (1.0f + e);
  return copysignf(t, x);
}

__device__ __forceinline__ void split8(const v4f& w0, const v4f& w1, v8h& hi, v8h& lo) {
#pragma unroll
  for (int u = 0; u < 4; ++u) {
    float v = w0[u]; _Float16 h = (_Float16)v;
    hi[u] = h; lo[u] = (_Float16)((v - (float)h) * 2048.0f);
  }
#pragma unroll
  for (int u = 0; u < 4; ++u) {
    float v = w1[u]; _Float16 h = (_Float16)v;
    hi[4+u] = h; lo[4+u] = (_Float16)((v - (float)h) * 2048.0f);
  }
}

__device__ __forceinline__ v8h cvt8(const v4f& w0, const v4f& w1) {
  v8h r;
#pragma unroll
  for (int u = 0; u < 4; ++u) { r[u] = (_Float16)w0[u]; r[4+u] = (_Float16)w1[u]; }
  return r;
}

// ---------------- K-1: normalize parent_valid to uchar[16384] ---------------
__global__ __launch_bounds__(256) void knorm(const void* __restrict__ pv_raw,
                                             unsigned char* __restrict__ pv8) {
  __shared__ int mode;
  const int tid = threadIdx.x;
  if (tid == 0) mode = 0;
  __syncthreads();
  const unsigned* pu = (const unsigned*)pv_raw;
  int local = 0;
  for (int i = tid; i < 4096; i += 256) {
    unsigned v = pu[i];
    if (v == 0x3F800000u) { local = 2; break; }
    if (v > 1u) local = 1;
  }
  if (local) atomicMax(&mode, local);
  __syncthreads();
  const int m = mode;
  const unsigned char* pb = (const unsigned char*)pv_raw;
  const float* pf = (const float*)pv_raw;
  const int* pi = (const int*)pv_raw;
  for (int i = tid; i < NTOK * 8; i += 256) {
    unsigned char v;
    if (m == 1)      v = (pb[i] != 0);
    else if (m == 2) v = (pf[i] != 0.0f);
    else             v = (pi[i] != 0);
    pv8[i] = v;
  }
}

// ---------------- K0: weight packing (vectorized) ---------------------------
__global__ __launch_bounds__(256) void kw_cvt(
    const float* __restrict__ a0, _Float16* __restrict__ f0,
    const float* __restrict__ a1, _Float16* __restrict__ f1,
    const float* __restrict__ a2, _Float16* __restrict__ f2,
    const float* __restrict__ a3, _Float16* __restrict__ f3) {
  const int t = blockIdx.x * 256 + threadIdx.x;
  if (t < 32768) {
    const int row = t >> 5, col8 = (t & 31) * 8;
    const int fc = row >> 4, l15 = row & 15;
    const int kk = col8 >> 5, lq = (col8 >> 3) & 3;
    const int lane8 = (lq * 16 + l15) * 8;
    const size_t srow = (size_t)row * 256 + col8;
    {
      v4f x0 = *(const v4f*)(a0 + srow), x1 = *(const v4f*)(a0 + srow + 4);
      *(v8h*)(f0 + (size_t)(fc * 8 + kk) * 512 + lane8) = cvt8(x0, x1);
    }
    {
      v4f x0 = *(const v4f*)(a1 + srow), x1 = *(const v4f*)(a1 + srow + 4);
      v8h hi, lo; split8(x0, x1, hi, lo);
      _Float16* d = f1 + (size_t)(fc * 8 + kk) * 1024 + lane8;
      *(v8h*)d = hi; *(v8h*)(d + 512) = lo;
    }
    {
      v4f x0 = *(const v4f*)(a2 + srow), x1 = *(const v4f*)(a2 + srow + 4);
      v8h hi, lo; split8(x0, x1, hi, lo);
      _Float16* d = f2 + (size_t)(fc * 8 + kk) * 1024 + lane8;
      *(v8h*)d = hi; *(v8h*)(d + 512) = lo;
    }
  } else {
    const int k = t - 32768;
    const int row = k >> 6, col8 = (k & 63) * 8;
    const int fc = row >> 4, l15 = row & 15;
    const int kk = col8 >> 5, lq = (col8 >> 3) & 3;
    const size_t srow = (size_t)row * 512 + col8;
    v4f x0 = *(const v4f*)(a3 + srow), x1 = *(const v4f*)(a3 + srow + 4);
    *(v8h*)(f3 + (size_t)(fc * 16 + kk) * 512 + (lq * 16 + l15) * 8) = cvt8(x0, x1);
  }
}

// ---------------- K1: Xg(fp16) = tokens_half @ Wih_tok^T (+biases) ----------
__global__ __launch_bounds__(512, 1) void kg2(const float* __restrict__ A,
                                              const _Float16* __restrict__ WtH,
                                              const float* __restrict__ b1,
                                              const float* __restrict__ b2,
                                              _Float16* __restrict__ Xg, int h) {
  __shared__ _Float16 As[64 * 520];
  const int tid  = threadIdx.x;
  const int lane = tid & 63;
  const int nq   = tid >> 6;
  const int l15  = lane & 15;
  const int lq   = lane >> 4;
  const int m0   = blockIdx.x * 64;

#pragma unroll
  for (int p = 0; p < 4; ++p) {
    const int row  = p * 16 + (tid >> 5);
    const int col0 = (tid & 31) * 16;
    const int ar   = m0 + row;
    const int tokrow = (ar & 2047) * 16 + h * 8 + (ar >> 11);
    const float* s = A + (size_t)tokrow * EE + col0;
    v4f x0 = *(const v4f*)s, x1 = *(const v4f*)(s + 4);
    v4f x2 = *(const v4f*)(s + 8), x3 = *(const v4f*)(s + 12);
    _Float16* d = As + row * 520 + col0;
    *(v8h*)d       = cvt8(x0, x1);
    *(v8h*)(d + 8) = cvt8(x2, x3);
  }
  __syncthreads();

  v4f acc[4][8];
#pragma unroll
  for (int n = 0; n < 8; ++n) {
    const int col = (nq * 8 + n) * 16 + l15;
    const float bb = b1[col] + b2[col];
#pragma unroll
    for (int m = 0; m < 4; ++m) acc[m][n] = (v4f){bb, bb, bb, bb};
  }

#pragma unroll 4
  for (int kk = 0; kk < 16; ++kk) {
    v8h af[4];
#pragma unroll
    for (int m = 0; m < 4; ++m)
      af[m] = *(const v8h*)(As + (m * 16 + l15) * 520 + kk * 32 + lq * 8);
#pragma unroll
    for (int n = 0; n < 8; ++n) {
      const int fc = nq * 8 + n;
      v8h bh = *(const v8h*)(WtH + (size_t)(fc * 16 + kk) * 512 + lane * 8);
#pragma unroll
      for (int m = 0; m < 4; ++m) acc[m][n] = mfma16(af[m], bh, acc[m][n]);
    }
  }

#pragma unroll
  for (int m = 0; m < 4; ++m)
#pragma unroll
    for (int n = 0; n < 8; ++n) {
      const int row = m0 + m * 16 + lq * 4;
      const int col = (nq * 8 + n) * 16 + l15;
      v4h o;
#pragma unroll
      for (int r = 0; r < 4; ++r) o[r] = (_Float16)acc[m][n][r];
      *(v4h*)(Xg + ((size_t)(row >> 2) * G4 + col) * 4) = o;
    }
}

// ---------------- K2: token LSTM recurrence (r12-proven 2-deep pipeline) ----
__global__ __launch_bounds__(512, 1) void kr3(const _Float16* __restrict__ Xg,
                                              const _Float16* __restrict__ WhhH,
                                              float* __restrict__ Hst,
                                              float* __restrict__ Cst,
                                              _Float16* __restrict__ emb, int q) {
  __shared__ float hbuf[2][16 * 260];
  const int tid  = threadIdx.x;
  const int lane = tid & 63;
  const int w    = tid >> 6;       // 0..7
  const int wv   = w & 3;
  const int jh   = w >> 2;
  const int l15  = lane & 15;
  const int lq   = lane >> 4;
  const int r0   = blockIdx.x * 16;

  const _Float16* wbase = WhhH + (size_t)(8 * jh + wv) * 4096 + lane * 8;

  v4f c[2];
  if (q) {
#pragma unroll
    for (int j2 = 0; j2 < 2; ++j2) {
      const int feat = 16 * (wv + 4 * (2 * jh + j2)) + l15;
#pragma unroll
      for (int r = 0; r < 4; ++r)
        c[j2][r] = Cst[(size_t)(r0 + lq * 4 + r) * HIDD + feat];
    }
    for (int idx = tid; idx < 4096; idx += 512)
      hbuf[0][(idx >> 8) * 260 + (idx & 255)] = Hst[(size_t)(r0 + (idx >> 8)) * HIDD + (idx & 255)];
  } else {
    c[0] = (v4f){0.f, 0.f, 0.f, 0.f};
    c[1] = (v4f){0.f, 0.f, 0.f, 0.f};
  }

  v4h xp[4][2];
  {
    const size_t xrow = (size_t)((r0 >> 2) + lq) * G4;
#pragma unroll
    for (int g = 0; g < 4; ++g)
#pragma unroll
      for (int j2 = 0; j2 < 2; ++j2) {
        const int col = 256 * g + 16 * (wv + 4 * (2 * jh + j2)) + l15;
        xp[g][j2] = *(const v4h*)(Xg + (xrow + col) * 4);
      }
  }

  v8h bA[8], bB[8];
#pragma unroll
  for (int g = 0; g < 4; ++g)
#pragma unroll
    for (int j2 = 0; j2 < 2; ++j2)
      bA[g * 2 + j2] = *(const v8h*)(wbase + (16 * g + 4 * j2) * 4096);
  __syncthreads();

#pragma unroll 1
  for (int tl = 0; tl < 8; ++tl) {
    const int cur = tl & 1;
    const bool have_h = (q > 0) || (tl > 0);
    v4f acc[4][2];
#pragma unroll
    for (int g = 0; g < 4; ++g)
#pragma unroll
      for (int j2 = 0; j2 < 2; ++j2) {
        v4f a;
#pragma unroll
        for (int r = 0; r < 4; ++r) a[r] = (float)xp[g][j2][r];
        acc[g][j2] = a;
      }
    if (tl < 7) {
      const size_t xrow = (size_t)((tl + 1) * 512 + (r0 >> 2) + lq) * G4;
#pragma unroll
      for (int g = 0; g < 4; ++g)
#pragma unroll
        for (int j2 = 0; j2 < 2; ++j2) {
          const int col = 256 * g + 16 * (wv + 4 * (2 * jh + j2)) + l15;
          xp[g][j2] = *(const v4h*)(Xg + (xrow + col) * 4);
        }
    }
    if (have_h) {
#pragma unroll
      for (int kp = 0; kp < 4; ++kp) {
        const int k0 = 2 * kp, k1 = 2 * kp + 1;
#pragma unroll
        for (int g = 0; g < 4; ++g)
#pragma unroll
          for (int j2 = 0; j2 < 2; ++j2)
            bB[g * 2 + j2] = *(const v8h*)(wbase + (16 * g + 4 * j2) * 4096 + k1 * 512);
        {
          const int ko = k0 * 32 + lq * 8;
          v4f w0 = *(const v4f*)(hbuf[cur] + l15 * 260 + ko);
          v4f w1 = *(const v4f*)(hbuf[cur] + l15 * 260 + ko + 4);
          v8h ah = cvt8(w0, w1);
#pragma unroll
          for (int g = 0; g < 4; ++g)
#pragma unroll
            for (int j2 = 0; j2 < 2; ++j2)
              acc[g][j2] = mfma16(ah, bA[g * 2 + j2], acc[g][j2]);
        }
        if (kp < 3) {
#pragma unroll
          for (int g = 0; g < 4; ++g)
#pragma unroll
            for (int j2 = 0; j2 < 2; ++j2)
              bA[g * 2 + j2] = *(const v8h*)(wbase + (16 * g + 4 * j2) * 4096 + (k1 + 1) * 512);
        }
        {
          const int ko = k1 * 32 + lq * 8;
          v4f w0 = *(const v4f*)(hbuf[cur] + l15 * 260 + ko);
          v4f w1 = *(const v4f*)(hbuf[cur] + l15 * 260 + ko + 4);
          v8h ah = cvt8(w0, w1);
#pragma unroll
          for (int g = 0; g < 4; ++g)
#pragma unroll
            for (int j2 = 0; j2 < 2; ++j2)
              acc[g][j2] = mfma16(ah, bB[g * 2 + j2], acc[g][j2]);
        }
      }
      if (tl < 7) {
#pragma unroll
        for (int g = 0; g < 4; ++g)
#pragma unroll
          for (int j2 = 0; j2 < 2; ++j2)
            bA[g * 2 + j2] = *(const v8h*)(wbase + (16 * g + 4 * j2) * 4096);
      }
    }
#pragma unroll
    for (int j2 = 0; j2 < 2; ++j2) {
      const int feat = 16 * (wv + 4 * (2 * jh + j2)) + l15;
#pragma unroll
      for (int r = 0; r < 4; ++r) {
        const int rr = lq * 4 + r;
        float cn = fsig(acc[1][j2][r]) * c[j2][r] + fsig(acc[0][j2][r]) * ftanh(acc[2][j2][r]);
        float hn = fsig(acc[3][j2][r]) * ftanh(cn);
        c[j2][r] = cn;
        hbuf[cur ^ 1][rr * 260 + feat] = hn;
        if (tl == 7) {
          const size_t grow = r0 + rr;
          if (!q) { Hst[grow * HIDD + feat] = hn; Cst[grow * HIDD + feat] = cn; }
          else    { emb[grow * HIDD + feat] = (_Float16)hn; }
        }
      }
    }
    __syncthreads();
  }
}

// ---------------- K2b: P = emb @ Wih_ins^T + (bi+bh), fp32 tiled ------------
__global__ __launch_bounds__(512, 1) void kxi(const _Float16* __restrict__ emb,
                                              const _Float16* __restrict__ WihF,
                                              const float* __restrict__ bi,
                                              const float* __restrict__ bh,
                                              float* __restrict__ P) {
  __shared__ _Float16 As[64 * 264];
  const int tid  = threadIdx.x;
  const int lane = tid & 63;
  const int nq   = tid >> 6;
  const int l15  = lane & 15;
  const int lq   = lane >> 4;
  const int m0   = blockIdx.x * 64;

#pragma unroll
  for (int p = 0; p < 4; ++p) {
    const int idx = tid + 512 * p;
    const int row = idx >> 5;
    const int c8  = (idx & 31) * 8;
    *(v8h*)(As + row * 264 + c8) = *(const v8h*)(emb + (size_t)(m0 + row) * HIDD + c8);
  }
  __syncthreads();

  v4f acc[4][8];
#pragma unroll
  for (int n = 0; n < 8; ++n) {
    const int col = (nq * 8 + n) * 16 + l15;
    const float bb = bi[col] + bh[col];
#pragma unroll
    for (int m = 0; m < 4; ++m) acc[m][n] = (v4f){bb, bb, bb, bb};
  }

#pragma unroll 2
  for (int kk = 0; kk < 8; ++kk) {
    v8h af[4];
#pragma unroll
    for (int m = 0; m < 4; ++m)
      af[m] = *(const v8h*)(As + (m * 16 + l15) * 264 + kk * 32 + lq * 8);
#pragma unroll
    for (int n = 0; n < 8; ++n) {
      const int fc = nq * 8 + n;
      v8h bhf = *(const v8h*)(WihF + (size_t)(fc * 8 + kk) * 1024 + lane * 8);
#pragma unroll
      for (int m = 0; m < 4; ++m) acc[m][n] = mfma16(af[m], bhf, acc[m][n]);
    }
  }

#pragma unroll
  for (int m = 0; m < 4; ++m)
#pragma unroll
    for (int n = 0; n < 8; ++n) {
      const int row = m0 + m * 16 + lq * 4;
      const int col = (nq * 8 + n) * 16 + l15;
      *(v4f*)(P + ((size_t)(row >> 2) * G4 + col) * 4) = acc[m][n];
    }
}

// ---------------- K3a: appears scatter (32 blocks) --------------------------
__global__ __launch_bounds__(256) void kapp(const int* __restrict__ pidx,
                                            const unsigned char* __restrict__ pval,
                                            int* __restrict__ appears) {
  int e = blockIdx.x * 512 + threadIdx.x * 2;
#pragma unroll
  for (int u = 0; u < 2; ++u, ++e) {
    if (pval[e]) atomicAdd(appears + pidx[e], 1);
  }
}

// ---------------- K3b: one DAG level (32 blocks) ----------------------------
__global__ __launch_bounds__(256) void klevel(
    const float* __restrict__ P,
    const _Float16* __restrict__ WhhF,
    const int* __restrict__ pidx, const unsigned char* __restrict__ pval,
    float* __restrict__ H, float* __restrict__ C, int l) {
  __shared__ _Float16 h0s[16 * 264];
  __shared__ float    c0s[16 * 68];
  __shared__ int      pis[128];
  __shared__ unsigned char pvs[128];
  const int tid  = threadIdx.x;
  const int lane = tid & 63;
  const int wv   = tid >> 6;
  const int l15  = lane & 15;
  const int lq   = lane >> 4;
  const int b    = blockIdx.x;
  const int mf   = b >> 2;
  const int q    = b & 3;
  const int fi   = q * 4 + wv;

  if (tid < 128) {
    int rr = tid >> 3, p = tid & 7;
    int row = l * KLVL + mf * 16 + rr;
    pis[tid] = pidx[row * 8 + p];
    pvs[tid] = pval[row * 8 + p];
  }
  __syncthreads();
#pragma unroll 1
  for (int it = 0; it < 4; ++it) {
    int task = tid + 256 * it;
    int rr = task >> 6;
    int f4 = (task & 63) * 4;
    v4f hm = (v4f){-1e30f, -1e30f, -1e30f, -1e30f};
    bool any = false;
#pragma unroll
    for (int p = 0; p < 8; ++p) {
      if (pvs[rr * 8 + p]) {
        any = true;
        v4f hv = *(const v4f*)(H + (size_t)pis[rr * 8 + p] * HIDD + f4);
#pragma unroll
        for (int u = 0; u < 4; ++u) hm[u] = fmaxf(hm[u], hv[u]);
      }
    }
    if (!any) hm = (v4f){0.f, 0.f, 0.f, 0.f};
    v4h h4;
#pragma unroll
    for (int u = 0; u < 4; ++u) h4[u] = (_Float16)hm[u];
    *(v4h*)(h0s + rr * 264 + f4) = h4;
  }
  {
    int rr = tid >> 4;
    int cc = (tid & 15) * 4;
    int f4 = q * 64 + cc;
    v4f cm = (v4f){-1e30f, -1e30f, -1e30f, -1e30f};
    bool any = false;
#pragma unroll
    for (int p = 0; p < 8; ++p) {
      if (pvs[rr * 8 + p]) {
        any = true;
        v4f cv = *(const v4f*)(C + (size_t)pis[rr * 8 + p] * HIDD + f4);
#pragma unroll
        for (int u = 0; u < 4; ++u) cm[u] = fmaxf(cm[u], cv[u]);
      }
    }
    if (!any) cm = (v4f){0.f, 0.f, 0.f, 0.f};
    *(v4f*)(c0s + rr * 68 + cc) = cm;
  }
  __syncthreads();

  v4f acc[4];
  const int lrow4 = l * 32 + mf * 4 + lq;
#pragma unroll
  for (int g = 0; g < 4; ++g)
    acc[g] = *(const v4f*)(P + ((size_t)lrow4 * G4 + 256 * g + 16 * fi + l15) * 4);

#pragma unroll 1
  for (int kk = 0; kk < 8; ++kk) {
    const int ko = kk * 32 + lq * 8;
    v8h ah = *(const v8h*)(h0s + l15 * 264 + ko);
#pragma unroll
    for (int g = 0; g < 4; ++g) {
      const int fc = 16 * g + fi;
      acc[g] = mfma16(ah, *(const v8h*)(WhhF + (size_t)(fc * 8 + kk) * 1024 + lane * 8), acc[g]);
    }
  }
#pragma unroll
  for (int r = 0; r < 4; ++r) {
    int rr = lq * 4 + r;
    int n  = 16 * fi + l15;
    float c0 = c0s[rr * 68 + 16 * wv + l15];
    float cn = fsig(acc[1][r]) * c0 + fsig(acc[0][r]) * ftanh(acc[2][r]);
    float hn = fsig(acc[3][r]) * ftanh(cn);
    int grow = l * KLVL + mf * 16 + rr;
    H[(size_t)grow * HIDD + n] = hn;
    C[(size_t)grow * HIDD + n] = cn;
  }
}

// ---------------- K4a: partial root max (32 blocks x 64 rows) ---------------
__global__ __launch_bounds__(256) void kroot1(const float* __restrict__ H,
                                              const int* __restrict__ appears,
                                              float* __restrict__ pmax) {
  __shared__ int app[64];
  const int tid = threadIdx.x;
  const int rb  = blockIdx.x * 64;
  if (tid < 64) app[tid] = appears[rb + tid];
  __syncthreads();
  float m = -1e30f;
#pragma unroll 1
  for (int r = 0; r < 64; ++r) {
    if (app[r] == 0) m = fmaxf(m, H[(size_t)(rb + r) * HIDD + tid]);
  }
  pmax[blockIdx.x * 256 + tid] = m;
}

// ---------------- K4b: final combine + linear -------------------------------
__global__ __launch_bounds__(256) void kroot2(const float* __restrict__ pmax,
                                              const float* __restrict__ Wlin,
                                              const float* __restrict__ blin,
                                              float* __restrict__ out) {
  __shared__ float red[256];
  const int tid = threadIdx.x;
  float m = pmax[tid];
#pragma unroll 1
  for (int bb = 1; bb < 32; ++bb) m = fmaxf(m, pmax[bb * 256 + tid]);
  red[tid] = m * Wlin[tid];
  __syncthreads();
  if (tid == 0) {
    float s = 0.f;
    for (int i2 = 0; i2 < 256; ++i2) s += red[i2];
    out[0] = s + blin[0];
  }
}

// ---------------- launch ----------------------------------------------------
extern "C" void kernel_launch(void* const* d_in, const int* in_sizes, int n_in,
                              void* d_out, int out_size, void* d_ws, size_t ws_size,
                              hipStream_t stream) {
  const float* tokens  = (const float*)d_in[0];
  const int*   pidx    = (const int*)d_in[1];
  const void*  pvraw   = (const void*)d_in[2];
  const float* Wih_tok = (const float*)d_in[3];
  const float* Whh_tok = (const float*)d_in[4];
  const float* bih_tok = (const float*)d_in[5];
  const float* bhh_tok = (const float*)d_in[6];
  const float* Wih_ins = (const float*)d_in[7];
  const float* Whh_ins = (const float*)d_in[8];
  const float* bih_ins = (const float*)d_in[9];
  const float* bhh_ins = (const float*)d_in[10];
  const float* Wlin    = (const float*)d_in[11];
  const float* blin    = (const float*)d_in[12];

  char* ws = (char*)d_ws;
  const size_t OFF_XG    = 0;                       // fp16 half 33.5 MB (reused)
  const size_t OFF_H     = OFF_XG   + 33554432;
  const size_t OFF_C     = OFF_H    + 2097152;
  const size_t OFF_EMB   = OFF_C    + 2097152;      // fp16 1 MB
  const size_t OFF_P     = OFF_EMB  + 1048576;      // fp32 tiled 8 MB
  const size_t OFF_WHHT  = OFF_P    + 8388608;      // Whh_tok hi-dense 512 KB
  const size_t OFF_WIHIF = OFF_WHHT + 524288;       // ins split 1 MB each
  const size_t OFF_WHHIF = OFF_WIHIF + 1048576;
  const size_t OFF_WTH   = OFF_WHHIF + 1048576;     // Wih_tok hi-dense 1 MB
  const size_t OFF_APP   = OFF_WTH  + 1048576;
  const size_t OFF_PMX   = OFF_APP  + 8192;
  const size_t OFF_PV8   = OFF_PMX  + 32768;

  _Float16* Xg    = (_Float16*)(ws + OFF_XG);
  float*    Hbuf  = (float*)(ws + OFF_H);
  float*    Cbuf  = (float*)(ws + OFF_C);
  _Float16* emb   = (_Float16*)(ws + OFF_EMB);
  float*    Pbuf  = (float*)(ws + OFF_P);
  _Float16* WhhT  = (_Float16*)(ws + OFF_WHHT);
  _Float16* WihIF = (_Float16*)(ws + OFF_WIHIF);
  _Float16* WhhIF = (_Float16*)(ws + OFF_WHHIF);
  _Float16* WtH   = (_Float16*)(ws + OFF_WTH);
  int*      app   = (int*)(ws + OFF_APP);
  float*    pmx   = (float*)(ws + OFF_PMX);
  unsigned char* pv8 = (unsigned char*)(ws + OFF_PV8);

  hipMemsetAsync(ws + OFF_APP, 0, 8192, stream);

  knorm<<<dim3(1), dim3(256), 0, stream>>>(pvraw, pv8);
  kw_cvt<<<dim3(384), dim3(256), 0, stream>>>(Whh_tok, WhhT,
                                              Wih_ins, WihIF,
                                              Whh_ins, WhhIF,
                                              Wih_tok, WtH);
  kapp<<<dim3(32), dim3(256), 0, stream>>>(pidx, pv8, app);

  for (int h = 0; h < 2; ++h) {
    kg2<<<dim3(256), dim3(512), 0, stream>>>(tokens, WtH, bih_tok, bhh_tok, Xg, h);
    kr3<<<dim3(128), dim3(512), 0, stream>>>(Xg, WhhT, Hbuf, Cbuf, emb, h);
  }

  kxi<<<dim3(32), dim3(512), 0, stream>>>(emb, WihIF, bih_ins, bhh_ins, Pbuf);

  for (int l = 0; l < NLVL; ++l) {
    klevel<<<dim3(32), dim3(256), 0, stream>>>(Pbuf, WhhIF, pidx, pv8,
                                               Hbuf, Cbuf, l);
  }
  kroot1<<<dim3(32), dim3(256), 0, stream>>>(Hbuf, app, pmx);
  kroot2<<<dim3(1), dim3(256), 0, stream>>>(pmx, Wlin, blin, (float*)d_out);
}